// Round 1
// baseline (202.871 us; speedup 1.0000x reference)
//
#include <hip/hip_runtime.h>

#define T_ 500
#define R_ 50
#define NS_ 1000
#define H1_ 32
#define H2_ 16
#define NEG_ 0.2f

__device__ __forceinline__ float lrelu(float x) { return x >= 0.f ? x : NEG_ * x; }

// y1[t][c] = sum_f x[t][f] * gc1_w[f][c]   (x = [state(2) | payoff_row(500) | noise(2)])
__global__ __launch_bounds__(256) void k1_xw(const float* __restrict__ state,
                                             const float* __restrict__ payoff,
                                             const float* __restrict__ noise,
                                             const float* __restrict__ w,
                                             float* __restrict__ y1) {
    int gid = blockIdx.x * 256 + threadIdx.x;
    if (gid >= T_ * H1_) return;
    int t = gid / H1_, c = gid % H1_;
    float acc = state[t * 2] * w[c] + state[t * 2 + 1] * w[H1_ + c];
    const float* prow = payoff + t * T_;
#pragma unroll 4
    for (int u = 0; u < T_; ++u) acc += prow[u] * w[(2 + u) * H1_ + c];
    acc += noise[t * 2] * w[502 * H1_ + c] + noise[t * 2 + 1] * w[503 * H1_ + c];
    y1[gid] = acc;
}

// h1[t][c] = lrelu((sum_u adj[t][u]*y1[u][c] + b[c]) * gamma[t] + beta[t])
__global__ __launch_bounds__(256) void k2_adj(const float* __restrict__ adj,
                                              const float* __restrict__ y1,
                                              const float* __restrict__ b,
                                              const float* __restrict__ gamma,
                                              const float* __restrict__ beta,
                                              float* __restrict__ h1) {
    int gid = blockIdx.x * 256 + threadIdx.x;
    if (gid >= T_ * H1_) return;
    int t = gid / H1_, c = gid % H1_;
    const float* arow = adj + t * T_;
    float acc = 0.f;
#pragma unroll 4
    for (int u = 0; u < T_; ++u) acc += arow[u] * y1[u * H1_ + c];
    h1[gid] = lrelu((acc + b[c]) * gamma[t] + beta[t]);
}

// y2[t][c2] = sum_c h1[t][c] * gc2_w[c][c2]
__global__ __launch_bounds__(256) void k3_xw2(const float* __restrict__ h1,
                                              const float* __restrict__ w,
                                              float* __restrict__ y2) {
    int gid = blockIdx.x * 256 + threadIdx.x;
    if (gid >= T_ * H2_) return;
    int t = gid / H2_, c2 = gid % H2_;
    float acc = 0.f;
#pragma unroll
    for (int c = 0; c < H1_; ++c) acc += h1[t * H1_ + c] * w[c * H2_ + c2];
    y2[gid] = acc;
}

// xf[t*16+c2] = lrelu((sum_u adj[t][u]*y2[u][c2] + b[c2]) * gamma[t] + beta[t])
__global__ __launch_bounds__(256) void k4_adj2(const float* __restrict__ adj,
                                               const float* __restrict__ y2,
                                               const float* __restrict__ b,
                                               const float* __restrict__ gamma,
                                               const float* __restrict__ beta,
                                               float* __restrict__ xf) {
    int gid = blockIdx.x * 256 + threadIdx.x;
    if (gid >= T_ * H2_) return;
    int t = gid / H2_, c2 = gid % H2_;
    const float* arow = adj + t * T_;
    float acc = 0.f;
#pragma unroll 4
    for (int u = 0; u < T_; ++u) acc += arow[u] * y2[u * H2_ + c2];
    xf[gid] = lrelu((acc + b[c2]) * gamma[t] + beta[t]);
}

// part[s][j] = sum_{k in chunk s} xf[k] * aw[k][j]   (k-split of xf @ actgen_w)
#define NSPLIT_ 40
#define KC_ 200
__global__ __launch_bounds__(256) void k5_shared(const float* __restrict__ xf,
                                                 const float* __restrict__ aw,
                                                 float* __restrict__ part) {
    int j = blockIdx.x * 256 + threadIdx.x;
    if (j >= T_) return;
    int s = blockIdx.y;
    int k0 = s * KC_;
    float acc = 0.f;
#pragma unroll 4
    for (int k = k0; k < k0 + KC_; ++k) acc += xf[k] * aw[k * T_ + j];
    part[s * T_ + j] = acc;
}

// logits[r][j] = sum_s part[s][j] + sum_t dloc[r][t] * av[t][j]
__global__ __launch_bounds__(256) void k6_logits(const float* __restrict__ part,
                                                 const float* __restrict__ dloc,
                                                 const float* __restrict__ av,
                                                 float* __restrict__ logits) {
    int gid = blockIdx.x * 256 + threadIdx.x;
    if (gid >= R_ * T_) return;
    int r = gid / T_, j = gid % T_;
    float acc = 0.f;
#pragma unroll
    for (int s = 0; s < NSPLIT_; ++s) acc += part[s * T_ + j];
    const float* drow = dloc + r * T_;
#pragma unroll 4
    for (int t = 0; t < T_; ++t) acc += drow[t] * av[t * T_ + j];
    logits[gid] = acc;
}

// One wave per softmax row: out[row][j] = softmax_j(logits[r][j] - log(-log(u[row][j])))
__global__ __launch_bounds__(256) void k7_softmax(const float* __restrict__ gu,
                                                  const float* __restrict__ logits,
                                                  float* __restrict__ out) {
    int wave = threadIdx.x >> 6;
    int lane = threadIdx.x & 63;
    int row = blockIdx.x * 4 + wave;  // < 50000
    int r = row % R_;
    const float* grow = gu + row * T_;
    const float* lrow = logits + r * T_;
    float v[8];
    float m = -1e30f;
#pragma unroll
    for (int i = 0; i < 8; ++i) {
        int j = lane + i * 64;
        if (j < T_) {
            float u = grow[j];
            float g = -__logf(-__logf(u));
            v[i] = lrow[j] + g;
            m = fmaxf(m, v[i]);
        } else {
            v[i] = -1e30f;
        }
    }
#pragma unroll
    for (int off = 32; off > 0; off >>= 1) m = fmaxf(m, __shfl_xor(m, off));
    float ssum = 0.f;
#pragma unroll
    for (int i = 0; i < 8; ++i) {
        int j = lane + i * 64;
        v[i] = (j < T_) ? __expf(v[i] - m) : 0.f;
        ssum += v[i];
    }
#pragma unroll
    for (int off = 32; off > 0; off >>= 1) ssum += __shfl_xor(ssum, off);
    float inv = 1.f / ssum;
    float* orow = out + row * T_;
#pragma unroll
    for (int i = 0; i < 8; ++i) {
        int j = lane + i * 64;
        if (j < T_) orow[j] = v[i] * inv;
    }
}

extern "C" void kernel_launch(void* const* d_in, const int* in_sizes, int n_in,
                              void* d_out, int out_size, void* d_ws, size_t ws_size,
                              hipStream_t stream) {
    const float* state  = (const float*)d_in[0];
    const float* dloc   = (const float*)d_in[1];
    const float* noise  = (const float*)d_in[2];
    const float* gu     = (const float*)d_in[3];
    const float* payoff = (const float*)d_in[4];
    const float* adj    = (const float*)d_in[5];
    const float* g1w    = (const float*)d_in[6];
    const float* g1b    = (const float*)d_in[7];
    const float* g2w    = (const float*)d_in[8];
    const float* g2b    = (const float*)d_in[9];
    const float* gamma  = (const float*)d_in[10];
    const float* beta   = (const float*)d_in[11];
    const float* aw     = (const float*)d_in[12];
    const float* av     = (const float*)d_in[13];
    float* out = (float*)d_out;

    float* ws     = (float*)d_ws;
    float* y1     = ws;          // 16000
    float* h1     = ws + 16000;  // 16000
    float* y2     = ws + 32000;  // 8000
    float* xf     = ws + 40000;  // 8000
    float* part   = ws + 48000;  // 40*500 = 20000
    float* logits = ws + 68000;  // 25000   (total 93000 floats = 372 KB)

    k1_xw<<<(T_ * H1_ + 255) / 256, 256, 0, stream>>>(state, payoff, noise, g1w, y1);
    k2_adj<<<(T_ * H1_ + 255) / 256, 256, 0, stream>>>(adj, y1, g1b, gamma, beta, h1);
    k3_xw2<<<(T_ * H2_ + 255) / 256, 256, 0, stream>>>(h1, g2w, y2);
    k4_adj2<<<(T_ * H2_ + 255) / 256, 256, 0, stream>>>(adj, y2, g2b, gamma, beta, xf);
    k5_shared<<<dim3(2, NSPLIT_), 256, 0, stream>>>(xf, aw, part);
    k6_logits<<<(R_ * T_ + 255) / 256, 256, 0, stream>>>(part, dloc, av, logits);
    k7_softmax<<<(NS_ * R_) / 4, 256, 0, stream>>>(gu, logits, out);
}

// Round 2
// 104.879 us; speedup vs baseline: 1.9343x; 1.9343x over previous
//
#include <hip/hip_runtime.h>

#define T_ 500
#define R_ 50
#define NS_ 1000
#define H1_ 32
#define H2_ 16
#define NEG_ 0.2f

#define NSP1_ 50    // splits for xf@aw (K=8000, chunk 160)
#define KC1_ 160
#define NSP2_ 10    // splits for dloc@av (K=500, chunk 50)
#define KC2_ 50

__device__ __forceinline__ float lrelu(float x) { return x >= 0.f ? x : NEG_ * x; }

// One block per t: y1[t][c] = sum_f x[t][f] * gc1_w[f][c],  x=[state(2)|payoff row(500)|noise(2)]
__global__ __launch_bounds__(256) void k1_xw(const float* __restrict__ state,
                                             const float* __restrict__ payoff,
                                             const float* __restrict__ noise,
                                             const float* __restrict__ w,
                                             float* __restrict__ y1) {
    __shared__ float xs[504];
    __shared__ float red[8][H1_];
    int t = blockIdx.x, tid = threadIdx.x;
    for (int u = tid; u < T_; u += 256) xs[2 + u] = payoff[t * T_ + u];
    if (tid == 0) {
        xs[0] = state[t * 2];     xs[1] = state[t * 2 + 1];
        xs[502] = noise[t * 2];   xs[503] = noise[t * 2 + 1];
    }
    __syncthreads();
    int c = tid & 31, kg = tid >> 5;   // 8 k-groups x 32 channels
    float acc = 0.f;
    for (int f = kg; f < 504; f += 8) acc += xs[f] * w[f * H1_ + c];
    red[kg][c] = acc;
    __syncthreads();
    if (tid < H1_) {
        float a = 0.f;
#pragma unroll
        for (int s = 0; s < 8; ++s) a += red[s][tid];
        y1[t * H1_ + tid] = a;
    }
}

// One block per t: h1row = lrelu(bn(adj[t]@y1 + b)); then y2[t][c2] = h1row @ g2w
__global__ __launch_bounds__(256) void k2_adj_fused(const float* __restrict__ adj,
                                                    const float* __restrict__ y1,
                                                    const float* __restrict__ b,
                                                    const float* __restrict__ gamma,
                                                    const float* __restrict__ beta,
                                                    const float* __restrict__ w2,
                                                    float* __restrict__ y2) {
    __shared__ float arow[T_];
    __shared__ float red[8][H1_];
    __shared__ float h1row[H1_];
    int t = blockIdx.x, tid = threadIdx.x;
    for (int u = tid; u < T_; u += 256) arow[u] = adj[t * T_ + u];
    __syncthreads();
    int c = tid & 31, kg = tid >> 5;
    float acc = 0.f;
    for (int u = kg; u < T_; u += 8) acc += arow[u] * y1[u * H1_ + c];
    red[kg][c] = acc;
    __syncthreads();
    if (tid < H1_) {
        float a = 0.f;
#pragma unroll
        for (int s = 0; s < 8; ++s) a += red[s][tid];
        h1row[tid] = lrelu((a + b[tid]) * gamma[t] + beta[t]);
    }
    __syncthreads();
    if (tid < H2_) {
        float a = 0.f;
#pragma unroll
        for (int cc = 0; cc < H1_; ++cc) a += h1row[cc] * w2[cc * H2_ + tid];
        y2[t * H2_ + tid] = a;
    }
}

// One block per t: xf[t*16+c2] = lrelu(bn(adj[t]@y2 + b2))
__global__ __launch_bounds__(256) void k4_adj2(const float* __restrict__ adj,
                                               const float* __restrict__ y2,
                                               const float* __restrict__ b2,
                                               const float* __restrict__ gamma,
                                               const float* __restrict__ beta,
                                               float* __restrict__ xf) {
    __shared__ float arow[T_];
    __shared__ float red[16][H2_];
    int t = blockIdx.x, tid = threadIdx.x;
    for (int u = tid; u < T_; u += 256) arow[u] = adj[t * T_ + u];
    __syncthreads();
    int c2 = tid & 15, kg = tid >> 4;  // 16 k-groups x 16 channels
    float acc = 0.f;
    for (int u = kg; u < T_; u += 16) acc += arow[u] * y2[u * H2_ + c2];
    red[kg][c2] = acc;
    __syncthreads();
    if (tid < H2_) {
        float a = 0.f;
#pragma unroll
        for (int s = 0; s < 16; ++s) a += red[s][tid];
        xf[t * H2_ + tid] = lrelu((a + b2[tid]) * gamma[t] + beta[t]);
    }
}

// Split-K partials of sharedJ[j] = xf @ aw : part1[s][j]
__global__ __launch_bounds__(256) void k5_shared(const float* __restrict__ xf,
                                                 const float* __restrict__ aw,
                                                 float* __restrict__ part1) {
    int j = blockIdx.x * 256 + threadIdx.x;
    if (j >= T_) return;
    int s = blockIdx.y;
    int k0 = s * KC1_;
    float acc = 0.f;
#pragma unroll 4
    for (int k = k0; k < k0 + KC1_; ++k) acc += xf[k] * aw[k * T_ + j];
    part1[s * T_ + j] = acc;
}

// Split-K partials of dloc @ av : part2[s][r*T+j]
__global__ __launch_bounds__(256) void k6_dlocav(const float* __restrict__ dloc,
                                                 const float* __restrict__ av,
                                                 float* __restrict__ part2) {
    int gid = blockIdx.x * 256 + threadIdx.x;
    if (gid >= R_ * T_) return;
    int r = gid / T_, j = gid % T_;
    int s = blockIdx.y;
    int t0 = s * KC2_;
    const float* drow = dloc + r * T_;
    float acc = 0.f;
#pragma unroll 5
    for (int t = t0; t < t0 + KC2_; ++t) acc += drow[t] * av[t * T_ + j];
    part2[s * R_ * T_ + gid] = acc;
}

// logits[r][j] = sum_s part1[s][j] + sum_s part2[s][r*T+j]
__global__ __launch_bounds__(256) void k6_reduce(const float* __restrict__ part1,
                                                 const float* __restrict__ part2,
                                                 float* __restrict__ logits) {
    int gid = blockIdx.x * 256 + threadIdx.x;
    if (gid >= R_ * T_) return;
    int j = gid % T_;
    float acc = 0.f;
#pragma unroll 10
    for (int s = 0; s < NSP1_; ++s) acc += part1[s * T_ + j];
#pragma unroll
    for (int s = 0; s < NSP2_; ++s) acc += part2[s * R_ * T_ + gid];
    logits[gid] = acc;
}

// One wave per softmax row: out[row][j] = softmax_j(logits[r][j] + gumbel(u[row][j]))
__global__ __launch_bounds__(256) void k7_softmax(const float* __restrict__ gu,
                                                  const float* __restrict__ logits,
                                                  float* __restrict__ out) {
    int wave = threadIdx.x >> 6;
    int lane = threadIdx.x & 63;
    int row = blockIdx.x * 4 + wave;  // < 50000
    int r = row % R_;
    const float* grow = gu + row * T_;
    const float* lrow = logits + r * T_;
    float v[8];
    float m = -1e30f;
#pragma unroll
    for (int i = 0; i < 8; ++i) {
        int j = lane + i * 64;
        if (j < T_) {
            float u = grow[j];
            float g = -__logf(-__logf(u));
            v[i] = lrow[j] + g;
            m = fmaxf(m, v[i]);
        } else {
            v[i] = -1e30f;
        }
    }
#pragma unroll
    for (int off = 32; off > 0; off >>= 1) m = fmaxf(m, __shfl_xor(m, off));
    float ssum = 0.f;
#pragma unroll
    for (int i = 0; i < 8; ++i) {
        int j = lane + i * 64;
        v[i] = (j < T_) ? __expf(v[i] - m) : 0.f;
        ssum += v[i];
    }
#pragma unroll
    for (int off = 32; off > 0; off >>= 1) ssum += __shfl_xor(ssum, off);
    float inv = 1.f / ssum;
    float* orow = out + row * T_;
#pragma unroll
    for (int i = 0; i < 8; ++i) {
        int j = lane + i * 64;
        if (j < T_) orow[j] = v[i] * inv;
    }
}

extern "C" void kernel_launch(void* const* d_in, const int* in_sizes, int n_in,
                              void* d_out, int out_size, void* d_ws, size_t ws_size,
                              hipStream_t stream) {
    const float* state  = (const float*)d_in[0];
    const float* dloc   = (const float*)d_in[1];
    const float* noise  = (const float*)d_in[2];
    const float* gu     = (const float*)d_in[3];
    const float* payoff = (const float*)d_in[4];
    const float* adj    = (const float*)d_in[5];
    const float* g1w    = (const float*)d_in[6];
    const float* g1b    = (const float*)d_in[7];
    const float* g2w    = (const float*)d_in[8];
    const float* g2b    = (const float*)d_in[9];
    const float* gamma  = (const float*)d_in[10];
    const float* beta   = (const float*)d_in[11];
    const float* aw     = (const float*)d_in[12];
    const float* av     = (const float*)d_in[13];
    float* out = (float*)d_out;

    float* ws     = (float*)d_ws;
    float* y1     = ws;           // 16000
    float* y2     = ws + 16000;   // 8000
    float* xf     = ws + 24000;   // 8000
    float* part1  = ws + 32000;   // 50*500   = 25000
    float* part2  = ws + 57000;   // 10*25000 = 250000
    float* logits = ws + 307000;  // 25000    (total 332000 floats = 1.33 MB)

    k1_xw<<<T_, 256, 0, stream>>>(state, payoff, noise, g1w, y1);
    k2_adj_fused<<<T_, 256, 0, stream>>>(adj, y1, g1b, gamma, beta, g2w, y2);
    k4_adj2<<<T_, 256, 0, stream>>>(adj, y2, g2b, gamma, beta, xf);
    k5_shared<<<dim3(2, NSP1_), 256, 0, stream>>>(xf, aw, part1);
    k6_dlocav<<<dim3((R_ * T_ + 255) / 256, NSP2_), 256, 0, stream>>>(dloc, av, part2);
    k6_reduce<<<(R_ * T_ + 255) / 256, 256, 0, stream>>>(part1, part2, logits);
    k7_softmax<<<(NS_ * R_) / 4, 256, 0, stream>>>(gu, logits, out);
}